// Round 9
// baseline (25.984 us; speedup 1.0000x reference)
//
#include <hip/hip_runtime.h>
#include <math.h>

#define SZ 256
#define KPTS 64
#define GROUPS 4
#define SEGS_PER (KPTS / GROUPS)   // 16 segments per thread
#define NBLK (4 * SZ * 2)          // 2048 prod blocks: bn(4) x i(256) x jq(2)
#define K_SIGN 100000.0f
#define INV_2PI 0.15915494309189535f
#define PI_F 3.14159265358979323846f
#define HALFPI_F 1.57079632679489662f
// 2*K_SIGN*log2(e): tanh(2K*c) = 1 - 2/(exp2(K2_LOG2E*c)+1)
#define K2_LOG2E 288539.00817779269f
// angle clip equivalent of cos clip +-(1-1e-5)
#define ANG_LO 4.4721373e-3f
#define ANG_HI 3.1371205e-0f
// atan minimax deg-9 on [0,1]
#define AT1 0.99997726f
#define AT3 -0.33262347f
#define AT5 0.19354346f
#define AT7 -0.11643287f
#define AT9 0.05265332f

__device__ __forceinline__ float fast_rcp(float x)  { return __builtin_amdgcn_rcpf(x); }
__device__ __forceinline__ float fast_sqrt(float x) { return __builtin_amdgcn_sqrtf(x); }
__device__ __forceinline__ float fast_exp2(float x) { return __builtin_amdgcn_exp2f(x); }

// DPP lane permute (old = src; all lanes valid for the ctrls we use)
template <int CTRL>
__device__ __forceinline__ float dpp_mov(float v) {
    return __int_as_float(__builtin_amdgcn_update_dpp(
        __float_as_int(v), __float_as_int(v), CTRL, 0xF, 0xF, false));
}
#define DPP_XOR1   0xB1   // quad_perm [1,0,3,2]
#define DPP_XOR2   0x4E   // quad_perm [2,3,0,1]
#define DPP_SHR4   0x114  // row_shr:4
#define DPP_SHR8   0x118  // row_shr:8
#define DPP_BC15   0x142  // row_bcast15
#define DPP_BC31   0x143  // row_bcast31

// unclamped-norm angle: atan2(y>=0, x) in [0, pi], poly err ~1e-5 rad
__device__ __forceinline__ float fast_atan2pos(float y, float x, float mo_r) {
    // mo_r = (other pixel's m) * rcp(m0*m1)  == 1/m for this pixel
    const float n = fminf(fabsf(x), y);
    const float t = n * mo_r;                 // in [0,1]
    const float s = t * t;
    float p = fmaf(s, fmaf(s, fmaf(s, fmaf(s, AT9, AT7), AT5), AT3), AT1);
    p *= t;                                   // atan(t) in [0, pi/4]
    float r = (y > fabsf(x)) ? (HALFPI_F - p) : p;
    r = (x < 0.0f) ? (PI_F - r) : r;
    return r;
}

// d_ws: ws[blk*4 + wave] per-wave max, 8192 floats, fully rewritten each call.

// grid = 2048 blocks (bn*256*jq), block = 256 threads.
// thread t: g = t&3 (16-seg group), slot = t>>2 in [0,64) -> TWO pixels
// j0 = jq*128 + 2*slot, j1 = j0+1 (same row i => shared mx, shared dxn).
__global__ __launch_bounds__(256, 8) void contour_prod_kernel(
    const float* __restrict__ contour,   // [4][64][2]
    float* __restrict__ out,             // [4][256][256] unnormalized
    float* __restrict__ ws)              // [8192] per-wave maxes
{
    __shared__ float2 cpt[KPTS + 1];

    const int blk = blockIdx.x;
    const int jq  = blk & 1;
    const int i   = (blk >> 1) & 255;
    const int bn  = blk >> 9;

    const int t = threadIdx.x;
    if (t < KPTS) {
        float2 p = ((const float2*)contour)[bn * KPTS + t];
        cpt[t] = p;
        if (t == 0) cpt[KPTS] = p;      // wraparound dup
    }
    __syncthreads();

    const int g    = t & 3;
    const int slot = t >> 2;
    const int j0   = (jq << 7) + (slot << 1);

    const float mx  = (float)i  * (1.0f / (float)SZ);
    const float my0 = (float)j0 * (1.0f / (float)SZ);
    const float my1 = my0 + (1.0f / (float)SZ);

    const int base = g * SEGS_PER;

    float2 cp = cpt[base];
    float dxc  = cp.x - mx;
    float dyc0 = cp.y - my0;
    float dyc1 = cp.y - my1;
    const float dx2c = dxc * dxc;
    float mn0  = fmaf(dyc0, dyc0, dx2c);
    float mn1  = fmaf(dyc1, dyc1, dx2c);
    float acc0 = 0.0f, acc1 = 0.0f;

    #pragma unroll
    for (int kk = 0; kk < SEGS_PER; ++kk) {
        const float2 cn = cpt[base + kk + 1];
        const float dxn  = cn.x - mx;            // shared between pixels
        const float dyn0 = cn.y - my0;
        const float dyn1 = cn.y - my1;
        const float dx2  = dxn * dxn;            // shared
        mn0 = fminf(mn0, fmaf(dyn0, dyn0, dx2));
        mn1 = fminf(mn1, fmaf(dyn1, dyn1, dx2));

        const float dd = dxc * dxn;              // shared
        const float cross0 = fmaf(dyc0, dxn, -dxc * dyn0);
        const float cross1 = fmaf(dyc1, dxn, -dxc * dyn1);
        const float dot0   = fmaf(dyc0, dyn0, dd);
        const float dot1   = fmaf(dyc1, dyn1, dd);
        const float y0 = fabsf(cross0);
        const float y1 = fabsf(cross1);

        // batched reciprocal for the two atan2 range reductions
        const float m0 = fmaxf(fabsf(dot0), y0);
        const float m1 = fmaxf(fabsf(dot1), y1);
        const float rr = fast_rcp(m0 * m1);
        float ang0 = fast_atan2pos(y0, dot0, m1 * rr);
        float ang1 = fast_atan2pos(y1, dot1, m0 * rr);
        // reference cos-clip +-(1-1e-5) == angle clip
        ang0 = fminf(fmaxf(ang0, ANG_LO), ANG_HI);
        ang1 = fminf(fmaxf(ang1, ANG_LO), ANG_HI);

        // tanh(2K*cross) pair with one batched rcp; exp2 arg clamped so the
        // product (e0+1)(e1+1) stays finite (no inf*0 NaN).
        const float e0 = fast_exp2(fminf(K2_LOG2E * cross0, 100.0f));
        const float e1 = fast_exp2(fminf(K2_LOG2E * cross1, 100.0f));
        const float f0 = e0 + 1.0f;
        const float f1 = e1 + 1.0f;
        const float r2 = fast_rcp(f0 * f1);
        const float s0 = fmaf(-2.0f, f1 * r2, 1.0f);   // tanh for pixel 0
        const float s1 = fmaf(-2.0f, f0 * r2, 1.0f);   // tanh for pixel 1

        acc0 = fmaf(s0, ang0, acc0);
        acc1 = fmaf(s1, ang1, acc1);

        dxc = dxn; dyc0 = dyn0; dyc1 = dyn1;
    }

    // 4-lane group combine via DPP quad-perm butterflies (all-VALU)
    acc0 += dpp_mov<DPP_XOR1>(acc0);
    acc0 += dpp_mov<DPP_XOR2>(acc0);
    acc1 += dpp_mov<DPP_XOR1>(acc1);
    acc1 += dpp_mov<DPP_XOR2>(acc1);
    mn0 = fminf(mn0, dpp_mov<DPP_XOR1>(mn0));
    mn0 = fminf(mn0, dpp_mov<DPP_XOR2>(mn0));
    mn1 = fminf(mn1, dpp_mov<DPP_XOR1>(mn1));
    mn1 = fminf(mn1, dpp_mov<DPP_XOR2>(mn1));

    const float prod0 = fabsf(acc0) * INV_2PI * fast_sqrt(mn0);
    const float prod1 = fabsf(acc1) * INV_2PI * fast_sqrt(mn1);
    if (g == 0) {
        ((float2*)out)[(((bn << 8) + i) << 7) + (jq << 6) + slot] =
            make_float2(prod0, prod1);
    }

    // wave max via DPP (quads already uniform), store from lane 63
    float wm = fmaxf(prod0, prod1);
    wm = fmaxf(wm, dpp_mov<DPP_SHR4>(wm));
    wm = fmaxf(wm, dpp_mov<DPP_SHR8>(wm));
    wm = fmaxf(wm, dpp_mov<DPP_BC15>(wm));
    wm = fmaxf(wm, dpp_mov<DPP_BC31>(wm));
    if ((t & 63) == 63)
        ws[(blk << 2) + (t >> 6)] = wm;
}

// 256 blocks x 256 threads. Each block re-reduces ws[0..8191] (32 KB, L2-hit),
// then normalizes its 1024-pixel chunk (float4 per thread).
__global__ __launch_bounds__(256) void contour_norm_kernel(
    float4* __restrict__ out,
    const float* __restrict__ ws)
{
    __shared__ float wred[4];
    __shared__ float smax;

    const int t = threadIdx.x;
    const float4* w4 = (const float4*)ws;   // 2048 float4

    float m = 0.0f;                          // prod >= 0
    #pragma unroll
    for (int r = 0; r < 8; ++r) {
        float4 v = w4[t + (r << 8)];
        m = fmaxf(m, fmaxf(fmaxf(v.x, v.y), fmaxf(v.z, v.w)));
    }
    #pragma unroll
    for (int off = 32; off > 0; off >>= 1)
        m = fmaxf(m, __shfl_down(m, off, 64));
    if ((t & 63) == 0) wred[t >> 6] = m;
    __syncthreads();
    if (t == 0)
        smax = fmaxf(fmaxf(wred[0], wred[1]), fmaxf(wred[2], wred[3]));
    __syncthreads();

    const float inv = 1.0f / smax;           // one IEEE divide
    const int idx = blockIdx.x * 256 + t;
    float4 v = out[idx];
    v.x *= inv; v.y *= inv; v.z *= inv; v.w *= inv;
    out[idx] = v;
}

extern "C" void kernel_launch(void* const* d_in, const int* in_sizes, int n_in,
                              void* d_out, int out_size, void* d_ws, size_t ws_size,
                              hipStream_t stream)
{
    const float* contour = (const float*)d_in[0];   // [2][2][64][2] fp32
    float* out = (float*)d_out;                     // [2][2][256][256] fp32
    float* ws  = (float*)d_ws;

    contour_prod_kernel<<<NBLK, SZ, 0, stream>>>(contour, out, ws);
    contour_norm_kernel<<<out_size / 4 / 256, 256, 0, stream>>>((float4*)out, ws);
}

// Round 10
// 21.140 us; speedup vs baseline: 1.2291x; 1.2291x over previous
//
#include <hip/hip_runtime.h>
#include <math.h>

#define SZ 256
#define KPTS 64
#define GROUPS 4
#define SEGS_PER (KPTS / GROUPS)   // 16 segments per thread
#define PX 4                       // pixels per thread
#define NBLK (4 * SZ)              // 1024 prod blocks: bn(4) x i(256)
#define K_SIGN 100000.0f
#define EPS_C 1e-5f
#define INV_2PI 0.15915494309189535f
#define PI_F 3.14159265358979323846f
// 2*K_SIGN*log2(e): tanh(2K*c) = 1 - 2/(exp2(K2_LOG2E*c)+1)
#define K2_LOG2E 288539.00817779269f

__device__ __forceinline__ float fast_rcp(float x)  { return __builtin_amdgcn_rcpf(x); }
__device__ __forceinline__ float fast_sqrt(float x) { return __builtin_amdgcn_sqrtf(x); }
__device__ __forceinline__ float fast_rsq(float x)  { return __builtin_amdgcn_rsqf(x); }
__device__ __forceinline__ float fast_exp2(float x) { return __builtin_amdgcn_exp2f(x); }

// tanh(2K*cross) = 1 - 2/(exp2(K2_LOG2E*cross)+1); saturates cleanly.
__device__ __forceinline__ float fast_tanh_k(float cross) {
    float t = fast_exp2(K2_LOG2E * cross);
    return fmaf(-2.0f, fast_rcp(t + 1.0f), 1.0f);
}

// acos approx (Abramowitz-Stegun 4.4.45), max err ~6.7e-5 rad.
__device__ __forceinline__ float fast_acos(float x) {
    float ax = fabsf(x);
    float s  = fast_sqrt(1.0f - ax);
    float p  = s * fmaf(ax, fmaf(ax, fmaf(ax, -0.0187292994f, 0.0742610037f),
                                  -0.2121143937f), 1.5707288f);
    return (x >= 0.0f) ? p : (PI_F - p);
}

// d_ws: ws[blk] = per-block max, blk in [0,1024); fully rewritten every call.

// grid = 1024 blocks (bn x i), block = 256 threads.
// thread t: g = t&3 (16-seg group), slot = t>>2 in [0,64) -> FOUR pixels
// j = 4*slot + q, q=0..3 (same row i => shared mx, dxn, dx2, dd).
__global__ __launch_bounds__(256, 4) void contour_prod_kernel(
    const float* __restrict__ contour,   // [4][64][2]
    float* __restrict__ out,             // [4][256][256] unnormalized
    float* __restrict__ ws)              // [1024] per-block maxes
{
    __shared__ float2 cpt[KPTS + 1];
    __shared__ float wred[4];

    const int blk = blockIdx.x;
    const int i   = blk & 255;
    const int bn  = blk >> 8;

    const int t = threadIdx.x;
    if (t < KPTS) {
        float2 p = ((const float2*)contour)[bn * KPTS + t];
        cpt[t] = p;
        if (t == 0) cpt[KPTS] = p;      // wraparound dup
    }
    __syncthreads();

    const int g    = t & 3;
    const int slot = t >> 2;
    const int j0   = slot << 2;

    const float mx  = (float)i  * (1.0f / (float)SZ);
    float my[PX];
    #pragma unroll
    for (int q = 0; q < PX; ++q)
        my[q] = (float)(j0 + q) * (1.0f / (float)SZ);

    const int base = g * SEGS_PER;

    float2 cp = cpt[base];
    float dxc = cp.x - mx;
    const float dx2c = dxc * dxc;
    float dyc[PX], mn[PX], acc[PX];
    #pragma unroll
    for (int q = 0; q < PX; ++q) {
        dyc[q] = cp.y - my[q];
        mn[q]  = fmaf(dyc[q], dyc[q], dx2c);
        acc[q] = 0.0f;
    }
    float n2c[PX];
    #pragma unroll
    for (int q = 0; q < PX; ++q) n2c[q] = mn[q];

    #pragma unroll
    for (int kk = 0; kk < SEGS_PER; ++kk) {
        const float2 cn = cpt[base + kk + 1];
        const float dxn = cn.x - mx;             // shared across 4 pixels
        const float dx2 = dxn * dxn;             // shared
        const float dd  = dxc * dxn;             // shared

        #pragma unroll
        for (int q = 0; q < PX; ++q) {
            const float dyn  = cn.y - my[q];
            const float n2n  = fmaf(dyn, dyn, dx2);
            mn[q] = fminf(mn[q], n2n);

            const float cross = fmaf(dyc[q], dxn, -dxc * dyn);
            const float dot   = fmaf(dyc[q], dyn, dd);

            float cosang = dot * fast_rsq(n2c[q] * n2n);
            cosang = fminf(fmaxf(cosang, -1.0f + EPS_C), 1.0f - EPS_C); // v_med3
            const float ang = fast_acos(cosang);
            const float sgn = fast_tanh_k(cross);

            acc[q] = fmaf(sgn, ang, acc[q]);

            dyc[q] = dyn;
            n2c[q] = n2n;
        }
        dxc = dxn;
    }

    // combine 4 segment-groups per pixel (4-lane butterflies)
    #pragma unroll
    for (int q = 0; q < PX; ++q) {
        acc[q] += __shfl_xor(acc[q], 1, 64);
        acc[q] += __shfl_xor(acc[q], 2, 64);
        mn[q] = fminf(mn[q], __shfl_xor(mn[q], 1, 64));
        mn[q] = fminf(mn[q], __shfl_xor(mn[q], 2, 64));
    }

    float prod[PX];
    #pragma unroll
    for (int q = 0; q < PX; ++q)
        prod[q] = fabsf(acc[q]) * INV_2PI * fast_sqrt(mn[q]);

    if (g == 0) {
        ((float4*)out)[((bn << 8) + i) * (SZ / 4) + slot] =
            make_float4(prod[0], prod[1], prod[2], prod[3]);
    }

    // block max -> plain store
    float wmax = fmaxf(fmaxf(prod[0], prod[1]), fmaxf(prod[2], prod[3]));
    #pragma unroll
    for (int off = 32; off > 0; off >>= 1)
        wmax = fmaxf(wmax, __shfl_down(wmax, off, 64));
    if ((t & 63) == 0) wred[t >> 6] = wmax;
    __syncthreads();
    if (t == 0)
        ws[blk] = fmaxf(fmaxf(wred[0], wred[1]), fmaxf(wred[2], wred[3]));
}

// 256 blocks x 256 threads. Each block re-reduces ws[0..1023] (4 KB, L2-hit),
// then normalizes its 1024-pixel chunk (float4 per thread).
__global__ __launch_bounds__(256) void contour_norm_kernel(
    float4* __restrict__ out,
    const float* __restrict__ ws)
{
    __shared__ float wred[4];
    __shared__ float smax;

    const int t = threadIdx.x;
    const float4* w4 = (const float4*)ws;   // 256 float4

    float4 v0 = w4[t];
    float m = fmaxf(fmaxf(v0.x, v0.y), fmaxf(v0.z, v0.w));
    #pragma unroll
    for (int off = 32; off > 0; off >>= 1)
        m = fmaxf(m, __shfl_down(m, off, 64));
    if ((t & 63) == 0) wred[t >> 6] = m;
    __syncthreads();
    if (t == 0)
        smax = fmaxf(fmaxf(wred[0], wred[1]), fmaxf(wred[2], wred[3]));
    __syncthreads();

    const float inv = 1.0f / smax;           // one IEEE divide
    const int idx = blockIdx.x * 256 + t;
    float4 v = out[idx];
    v.x *= inv; v.y *= inv; v.z *= inv; v.w *= inv;
    out[idx] = v;
}

extern "C" void kernel_launch(void* const* d_in, const int* in_sizes, int n_in,
                              void* d_out, int out_size, void* d_ws, size_t ws_size,
                              hipStream_t stream)
{
    const float* contour = (const float*)d_in[0];   // [2][2][64][2] fp32
    float* out = (float*)d_out;                     // [2][2][256][256] fp32
    float* ws  = (float*)d_ws;

    contour_prod_kernel<<<NBLK, SZ, 0, stream>>>(contour, out, ws);
    contour_norm_kernel<<<out_size / 4 / 256, 256, 0, stream>>>((float4*)out, ws);
}